// Round 6
// baseline (94.047 us; speedup 1.0000x reference)
//
#include <hip/hip_runtime.h>

#define EPSF 1e-6f
#define POISON 0xAAAAAAAAu
#define INFB 0x7F800000u
#define WAVE_ROR1 0x13C   // DPP ctrl: rotate all 64 lanes by 1 (64 steps = identity)

template<int C>
__device__ __forceinline__ float dppf(float x) {
    return __int_as_float(__builtin_amdgcn_update_dpp(0, __float_as_int(x), C, 0xF, 0xF, true));
}

__device__ __forceinline__ float wave_sum(float v) {
#pragma unroll
    for (int off = 32; off; off >>= 1) v += __shfl_down(v, off, 64);
    return v;
}

// 512 blocks (one per image row) x 512 threads (8 waves).
// Wave w owns GT chunk w: lane s preloads GT[64w+s] as {dy^2, gx} in 2 VGPRs.
// Lane s owns pixels x = s + {0,64,...,448}. Per iter: 8 pairs vs the
// lane-resident GT point, then rotate {dy2, gx, acc} one lane via wave_ror1
// DPP. gt and acc rotate with the SAME ctrl, so column/acc alignment holds
// regardless of rotation direction; after 64 rotations everything is home.
// K-loop has ZERO DS/VMEM ops -> no lgkm serialization (R5's stall source).
// Column merge: each (block, column) belongs to exactly one wave -> one
// global atomicMin per lane at the end (64 consecutive dwords, free).
// Workspace poison contract (0xAA): g_cm uint-min identity (0xAAAAAAAA > any
// positive-float bits); sums poison -3.03e-13f absorbed by fp32 +=; cnt
// last-block check accepts POISON+511 (and 511 fallback).
__launch_bounds__(512, 4)
__global__ void chamfer_fused(const float* __restrict__ prob,
                              const float* __restrict__ gt,
                              float* __restrict__ out,
                              float* __restrict__ sums,        // [0]=sum p, [1]=sum p*d
                              unsigned int* __restrict__ cnt,
                              unsigned int* __restrict__ g_cm) // [16 slots][512]
{
    __shared__ unsigned int rm_s[512];   // per-pixel row-min d^2 bits
    __shared__ float p_s[512];
    __shared__ float red[16];
    __shared__ int last_s;

    const int t = threadIdx.x;
    const int row = blockIdx.x;
    const int s = t & 63;
    const float maxd = __builtin_sqrtf(524288.0f);   // sqrt(512^2+512^2)
    const float eod = EPSF / maxd;

    // ---- preload this lane's GT point into registers (t == GT index)
    float2 gv = ((const float2*)gt)[t];              // (gy, gx)
    float dyr = (float)row - gv.x;
    float g_dy2 = dyr * dyr;
    float g_gx  = gv.y;

    rm_s[t] = INFB;
    p_s[t] = prob[(row << 9) + t];
    __syncthreads();

    // ---- per-pixel constants for the 8 owned pixels x = s + 64k
    float inv[8], ei[8], rm[8];
#pragma unroll
    for (int k = 0; k < 8; ++k) {
        float p = p_s[s + (k << 6)];
        float q = p * p;
        float iv = 1.0f / (q * q + eod);
        inv[k] = iv;
        ei[k] = EPSF * iv;
        rm[k] = 3e38f;
    }
    const float sf = (float)s;

    // ---- main loop: 64 GT points circulate through the lanes; pure VALU/DPP
    float acc = __uint_as_float(INFB);
#pragma unroll 8
    for (int i = 0; i < 64; ++i) {
        float dx0 = sf - g_gx;
        float vm;
#pragma unroll
        for (int k = 0; k < 8; ++k) {
            float dx = dx0 + (float)(k << 6);
            float d2 = fmaf(dx, dx, g_dy2);
            rm[k] = fminf(rm[k], d2);
            float d = __builtin_amdgcn_sqrtf(d2);
            float vv = fmaf(d, inv[k], ei[k]);       // (d+eps)*inv
            vm = k ? fminf(vm, vv) : vv;
        }
        acc = fminf(dppf<WAVE_ROR1>(acc), vm);       // acc follows its column
        g_gx  = dppf<WAVE_ROR1>(g_gx);               // rotate GT to next lane
        g_dy2 = dppf<WAVE_ROR1>(g_dy2);
    }
    acc = dppf<WAVE_ROR1>(acc);                      // 64th rotation: home

    // ---- column merge: this wave exclusively owns columns 64w..64w+63
    atomicMin(&g_cm[((row & 15) << 9) + t], __float_as_uint(acc));

    // ---- row-min merge across the 8 waves (positive floats: bit-ordered)
#pragma unroll
    for (int k = 0; k < 8; ++k)
        atomicMin(&rm_s[s + (k << 6)], __float_as_uint(rm[k]));
    __syncthreads();

    // ---- term1 partials
    float dmin = __builtin_amdgcn_sqrtf(__uint_as_float(rm_s[t]));
    float pv = wave_sum(p_s[t] * dmin);
    float sp = wave_sum(p_s[t]);
    if ((t & 63) == 0) { red[t >> 6] = pv; red[8 + (t >> 6)] = sp; }
    __syncthreads();
    if (t == 0) {
        float a = 0.f, b = 0.f;
#pragma unroll
        for (int i = 0; i < 8; ++i) { a += red[i]; b += red[8 + i]; }
        atomicAdd(&sums[1], a);
        atomicAdd(&sums[0], b);
        __threadfence();
        unsigned int old = atomicAdd(cnt, 1u);
        last_s = (old == POISON + 511u) || (old == 511u);
    }
    __syncthreads();
    if (!last_s) return;

    // ---- last block finalizes
    __threadfence();
    unsigned int mv = __hip_atomic_load(&g_cm[t], __ATOMIC_RELAXED, __HIP_MEMORY_SCOPE_AGENT);
#pragma unroll
    for (int sl = 1; sl < 16; ++sl) {
        unsigned int u = __hip_atomic_load(&g_cm[(sl << 9) + t], __ATOMIC_RELAXED, __HIP_MEMORY_SCOPE_AGENT);
        mv = (u < mv) ? u : mv;
    }
    float v = fminf(fmaxf(__uint_as_float(mv), 0.0f), maxd);
    float s2 = wave_sum(v);
    if ((t & 63) == 0) red[t >> 6] = s2;
    __syncthreads();
    if (t == 0) {
        float tsum = 0.f;
#pragma unroll
        for (int i = 0; i < 8; ++i) tsum += red[i];
        float term2 = tsum * (1.0f / 512.0f);
        float sA = __hip_atomic_load(&sums[0], __ATOMIC_RELAXED, __HIP_MEMORY_SCOPE_AGENT);
        float sB = __hip_atomic_load(&sums[1], __ATOMIC_RELAXED, __HIP_MEMORY_SCOPE_AGENT);
        out[0] = sB / (sA + EPSF) + term2;
    }
}

extern "C" void kernel_launch(void* const* d_in, const int* in_sizes, int n_in,
                              void* d_out, int out_size, void* d_ws, size_t ws_size,
                              hipStream_t stream) {
    const float* prob = (const float*)d_in[0];   // [512*512]
    const float* gt   = (const float*)d_in[1];   // [512,2]
    // d_in[2] (all_img_locations) implicit from pixel index; unused.
    float* out = (float*)d_out;

    float* sums        = (float*)d_ws;                        // 8 B
    unsigned int* cnt  = (unsigned int*)((char*)d_ws + 8);    // 4 B
    unsigned int* g_cm = (unsigned int*)((char*)d_ws + 128);  // 16*512*4 = 32 KB

    chamfer_fused<<<512, 512, 0, stream>>>(prob, gt, out, sums, cnt, g_cm);
}